// Round 23
// baseline (179.891 us; speedup 1.0000x reference)
//
#include <hip/hip_runtime.h>
#include <hip/hip_fp16.h>
#include <math.h>

#define NNODES 100000
#define NEG_SLOPE 0.2f
#define FIN 500
#define KP 512     // padded K
#define HID 128    // heads*hidden
#define NH 4
#define BMG 128    // gemm rows per block (4 waves x 32 rows)

typedef __attribute__((ext_vector_type(8))) _Float16 half8v;
typedef __attribute__((ext_vector_type(4))) float f32x4;

__device__ __forceinline__ float lrelu(float x) { return x > 0.f ? x : NEG_SLOPE * x; }

__device__ __forceinline__ float sel4(float a0, float a1, float a2, float a3, int h) {
  float r = a0;
  r = (h == 1) ? a1 : r;
  r = (h == 2) ? a2 : r;
  r = (h == 3) ? a3 : r;
  return r;
}

// r8-proven conflict-free tile layout (measured SQ_LDS_BANK_CONFLICT = 0)
__device__ __forceinline__ int tile_off(int col, int slot) {
  return col * 32 + ((slot ^ ((col >> 1) & 3)) << 3);
}

// ---------------- prep: W1 -> pre-swizzled fp16 image  +  CSR offsets ----------------
__global__ __launch_bounds__(256) void prep_kernel(const float* __restrict__ W1,
                                                   _Float16* __restrict__ BT_sw,
                                                   const int* __restrict__ dst, int E,
                                                   int* __restrict__ off) {
  int b = blockIdx.x;
  if (b < 256) {
    int p = b * 256 + threadIdx.x;  // 65536
    int tile = p >> 12;
    int rem = p & 4095;
    int col = rem >> 5;
    int sw = (rem >> 3) & 3;
    int elem = rem & 7;
    int slot = sw ^ ((col >> 1) & 3);
    int k = tile * 32 + slot * 8 + elem;
    float v = (k < FIN) ? W1[k * HID + col] : 0.f;
    BT_sw[p] = (_Float16)v;
  } else {
    int n = (b - 256) * 256 + threadIdx.x;
    if (n > NNODES) return;
    int lo = 0, hi = E;
    while (lo < hi) {
      int mid = (lo + hi) >> 1;
      if (dst[mid] < n) lo = mid + 1; else hi = mid;
    }
    off[n] = lo;
  }
}

// ---------------- GEMM1: T4 counted-vmcnt + reg-staged fp16 A (48KB LDS) — r22, frozen ----------------
__global__ __launch_bounds__(256, 3) void gemm1_mfma_kernel(const float* __restrict__ A,
                                                            const _Float16* __restrict__ BT_sw,
                                                            const float* __restrict__ al,
                                                            const float* __restrict__ ar,
                                                            __half* __restrict__ z1h,
                                                            float* __restrict__ el,
                                                            float* __restrict__ er) {
  __shared__ __align__(16) _Float16 Ash[3][4096];  // 3 x 8KB fp16 A tiles
  __shared__ __align__(16) _Float16 Bsh[3][4096];  // 3 x 8KB fp16 B tiles

  const int t = threadIdx.x;
  const int w = t >> 6, lane = t & 63;
  const int fr = lane & 15, ko = lane >> 4;
  const int bm = blockIdx.x * BMG;

  const int rowl = t >> 1, khalf = t & 1;
  const int arow = min(bm + rowl, NNODES - 1);
  const float* pArow = A + (size_t)arow * FIN;
  const int aoff0 = tile_off(rowl, khalf * 2);
  const int aoff1 = tile_off(rowl, khalf * 2 + 1);

#define LOAD_A(S, R0, R1, R2, R3)                                  \
  do {                                                             \
    const float* pa = pArow + (S) * 32 + khalf * 16;               \
    R0 = *(const f32x4*)(pa);                                      \
    R1 = *(const f32x4*)(pa + 4);                                  \
    R2 = *(const f32x4*)(pa + 8);                                  \
    R3 = *(const f32x4*)(pa + 12);                                 \
  } while (0)

#define LOAD_A_EDGE(R0, R1, R2, R3)                                  \
  do {                                                               \
    const float* pa = pArow + 480 + khalf * 16;                      \
    int _e1 = khalf ? 0 : 4, _e2 = khalf ? 0 : 8, _e3 = khalf ? 0 : 12; \
    R0 = *(const f32x4*)(pa);                                        \
    R1 = *(const f32x4*)(pa + _e1);                                  \
    R2 = *(const f32x4*)(pa + _e2);                                  \
    R3 = *(const f32x4*)(pa + _e3);                                  \
  } while (0)

#define CONV_WRITE(BUF, S, R0, R1, R2, R3)                         \
  do {                                                             \
    half8v h0, h1;                                                 \
    _Pragma("unroll")                                              \
    for (int i = 0; i < 4; i++) {                                  \
      h0[i] = (_Float16)R0[i];                                     \
      h0[i + 4] = (_Float16)R1[i];                                 \
      h1[i] = (_Float16)R2[i];                                     \
      h1[i + 4] = (_Float16)R3[i];                                 \
    }                                                              \
    if ((S) == 15 && khalf) {                                      \
      _Pragma("unroll")                                            \
      for (int i = 0; i < 4; i++) h0[i + 4] = (_Float16)0.f;       \
      _Pragma("unroll")                                            \
      for (int i = 0; i < 8; i++) h1[i] = (_Float16)0.f;           \
    }                                                              \
    *(half8v*)&Ash[BUF][aoff0] = h0;                               \
    *(half8v*)&Ash[BUF][aoff1] = h1;                               \
  } while (0)

#define STAGE_B(BUF, S)                                                                     \
  do {                                                                                      \
    _Pragma("unroll")                                                                       \
    for (int j = 0; j < 2; j++) {                                                           \
      int c = j * 256 + w * 64 + lane;                                                      \
      const _Float16* src = BT_sw + (size_t)(S) * 4096 + c * 8;                             \
      __builtin_amdgcn_global_load_lds(                                                     \
          (const __attribute__((address_space(1))) unsigned int*)src,                       \
          (__attribute__((address_space(3))) unsigned int*)&Bsh[BUF][c * 8], 16, 0, 0);     \
    }                                                                                       \
  } while (0)

  f32x4 acc[2][8];
#pragma unroll
  for (int i = 0; i < 2; i++)
#pragma unroll
    for (int j = 0; j < 8; j++) acc[i][j] = (f32x4){0.f, 0.f, 0.f, 0.f};

#define COMPUTE_STEP(BUF)                                                                   \
  do {                                                                                      \
    _Pragma("unroll")                                                                       \
    for (int mi = 0; mi < 2; mi++) {                                                        \
      half8v af = *(half8v*)&Ash[BUF][tile_off(w * 32 + mi * 16 + fr, ko)];                 \
      _Pragma("unroll")                                                                     \
      for (int ni = 0; ni < 8; ni++) {                                                      \
        half8v bf = *(half8v*)&Bsh[BUF][tile_off(ni * 16 + fr, ko)];                        \
        acc[mi][ni] = __builtin_amdgcn_mfma_f32_16x16x32_f16(af, bf, acc[mi][ni], 0, 0, 0); \
      }                                                                                     \
    }                                                                                       \
  } while (0)

  f32x4 e0, e1, e2, e3, o0, o1, o2, o3;

  LOAD_A(0, e0, e1, e2, e3);
  STAGE_B(0, 0);
  LOAD_A(1, o0, o1, o2, o3);
  STAGE_B(1, 1);

#pragma unroll
  for (int s = 0; s < 16; ++s) {
    const int cb = s % 3;
    if (s <= 14) {
      asm volatile("s_waitcnt vmcnt(6)" ::: "memory");
    } else {
      asm volatile("s_waitcnt vmcnt(0)" ::: "memory");
    }
    __builtin_amdgcn_sched_barrier(0);
    if ((s & 1) == 0) {
      CONV_WRITE(cb, s, e0, e1, e2, e3);
    } else {
      CONV_WRITE(cb, s, o0, o1, o2, o3);
    }
    asm volatile("s_waitcnt lgkmcnt(0)" ::: "memory");
    __builtin_amdgcn_sched_barrier(0);
    __builtin_amdgcn_s_barrier();
    __builtin_amdgcn_sched_barrier(0);
    if (s + 2 <= 14) {
      if ((s & 1) == 0) {
        LOAD_A(s + 2, e0, e1, e2, e3);
      } else {
        LOAD_A(s + 2, o0, o1, o2, o3);
      }
      STAGE_B((s + 2) % 3, s + 2);
    } else if (s + 2 == 15) {
      LOAD_A_EDGE(o0, o1, o2, o3);
      STAGE_B((s + 2) % 3, 15);
    }
    COMPUTE_STEP(cb);
  }

#undef LOAD_A
#undef LOAD_A_EDGE
#undef CONV_WRITE
#undef STAGE_B
#undef COMPUTE_STEP

  float alv[8], arv[8];
#pragma unroll
  for (int ni = 0; ni < 8; ni++) {
    alv[ni] = al[ni * 16 + fr];
    arv[ni] = ar[ni * 16 + fr];
  }
#pragma unroll
  for (int mi = 0; mi < 2; mi++) {
#pragma unroll
    for (int r = 0; r < 4; r++) {
      int grow = bm + w * 32 + mi * 16 + ko * 4 + r;
      bool ok = grow < NNODES;
      if (ok) {
#pragma unroll
        for (int ni = 0; ni < 8; ni++)
          z1h[(size_t)grow * HID + ni * 16 + fr] = __float2half(acc[mi][ni][r]);
      }
#pragma unroll
      for (int h = 0; h < 4; h++) {
        float cl = acc[mi][2 * h][r] * alv[2 * h] + acc[mi][2 * h + 1][r] * alv[2 * h + 1];
        float cr = acc[mi][2 * h][r] * arv[2 * h] + acc[mi][2 * h + 1][r] * arv[2 * h + 1];
#pragma unroll
        for (int m = 1; m <= 8; m <<= 1) {
          cl += __shfl_xor(cl, m);
          cr += __shfl_xor(cr, m);
        }
        if (fr == 0 && ok) {
          el[grow * NH + h] = cl;
          er[grow * NH + h] = cr;
        }
      }
    }
  }
}

// ---------------- layer-1 + proj2 FUSED: SINGLE-PASS no-max softmax-agg ----------------
// No scoring pass, no LDS, no barriers. Per 8 edges: each slot's 16 col-lanes load
// src[e] + el4[sa] (same-address broadcast), compute p locally, gather z1h chunk, fma.
// Per-head denominator accumulated per-lane; folded into the 2-shfl slot-combine.
__global__ __launch_bounds__(256) void gat1_agg_kernel(const __half* __restrict__ z1h,
                                                       const float* __restrict__ el,
                                                       const float* __restrict__ er,
                                                       const int* __restrict__ src,
                                                       const int* __restrict__ off,
                                                       const float* __restrict__ b1,
                                                       const float* __restrict__ W2,
                                                       const float* __restrict__ al2,
                                                       const float* __restrict__ ar2,
                                                       float4* __restrict__ z2el,
                                                       float* __restrict__ er2) {
  int wid = threadIdx.x >> 6, lane = threadIdx.x & 63;
  int n = blockIdx.x * 4 + wid;
  if (n >= NNODES) return;

  int start = off[n], end = off[n + 1];
  const float4* el4 = reinterpret_cast<const float4*>(el);
  float4 er4 = reinterpret_cast<const float4*>(er)[n];

  const int g = lane >> 4;        // edge slot (0..3)
  const int c4 = lane & 15;       // col group: cols c4*8 .. c4*8+7
  const int headc = c4 >> 2;      // head of my col group
  const float erh = sel4(er4.x, er4.y, er4.z, er4.w, headc);

  float aA0 = 0.f, aA1 = 0.f, aA2 = 0.f, aA3 = 0.f;
  float aA4 = 0.f, aA5 = 0.f, aA6 = 0.f, aA7 = 0.f;
  float aB0 = 0.f, aB1 = 0.f, aB2 = 0.f, aB3 = 0.f;
  float aB4 = 0.f, aB5 = 0.f, aB6 = 0.f, aB7 = 0.f;
  float dA = 0.f, dB = 0.f;

  for (int i = start; i < end; i += 8) {
    int ea = i + g, eb = i + 4 + g;
    bool va_ = ea < end, vb_ = eb < end;
    int sa = src[va_ ? ea : start];   // start < end inside loop -> always valid
    int sb = src[vb_ ? eb : start];
    float4 xa = el4[sa];              // 16 lanes same address: broadcast
    float4 xb = el4[sb];
    float pa = va_ ? __expf(lrelu(sel4(xa.x, xa.y, xa.z, xa.w, headc) + erh)) : 0.f;
    float pb = vb_ ? __expf(lrelu(sel4(xb.x, xb.y, xb.z, xb.w, headc) + erh)) : 0.f;
    dA += pa;
    dB += pb;
    uint4 ra = reinterpret_cast<const uint4*>(z1h + (size_t)sa * HID)[c4];
    uint4 rb = reinterpret_cast<const uint4*>(z1h + (size_t)sb * HID)[c4];
    float2 va0 = __half22float2(*(__half2*)&ra.x);
    float2 va1 = __half22float2(*(__half2*)&ra.y);
    float2 va2 = __half22float2(*(__half2*)&ra.z);
    float2 va3 = __half22float2(*(__half2*)&ra.w);
    aA0 = fmaf(pa, va0.x, aA0); aA1 = fmaf(pa, va0.y, aA1);
    aA2 = fmaf(pa, va1.x, aA2); aA3 = fmaf(pa, va1.y, aA3);
    aA4 = fmaf(pa, va2.x, aA4); aA5 = fmaf(pa, va2.y, aA5);
    aA6 = fmaf(pa, va3.x, aA6); aA7 = fmaf(pa, va3.y, aA7);
    float2 vb0 = __half22float2(*(__half2*)&rb.x);
    float2 vb1 = __half22float2(*(__half2*)&rb.y);
    float2 vb2 = __half22float2(*(__half2*)&rb.z);
    float2 vb3 = __half22float2(*(__half2*)&rb.w);
    aB0 = fmaf(pb, vb0.x, aB0); aB1 = fmaf(pb, vb0.y, aB1);
    aB2 = fmaf(pb, vb1.x, aB2); aB3 = fmaf(pb, vb1.y, aB3);
    aB4 = fmaf(pb, vb2.x, aB4); aB5 = fmaf(pb, vb2.y, aB5);
    aB6 = fmaf(pb, vb3.x, aB6); aB7 = fmaf(pb, vb3.y, aB7);
  }

  // merge unroll chains
  float acc0 = aA0 + aB0, acc1 = aA1 + aB1, acc2 = aA2 + aB2, acc3 = aA3 + aB3;
  float acc4 = aA4 + aB4, acc5 = aA5 + aB5, acc6 = aA6 + aB6, acc7 = aA7 + aB7;
  float d = dA + dB;

  // combine the 4 edge slots (lanes {L, L^16, L^32, L^48} share c4): acc and d together
#pragma unroll
  for (int msk = 16; msk <= 32; msk <<= 1) {
    acc0 += __shfl_xor(acc0, msk); acc1 += __shfl_xor(acc1, msk);
    acc2 += __shfl_xor(acc2, msk); acc3 += __shfl_xor(acc3, msk);
    acc4 += __shfl_xor(acc4, msk); acc5 += __shfl_xor(acc5, msk);
    acc6 += __shfl_xor(acc6, msk); acc7 += __shfl_xor(acc7, msk);
    d += __shfl_xor(d, msk);
  }

  if (g == 0) {  // lanes 0..15: full h1 row in registers (8 cols each), d = full denom(headc)
    float inv = 1.f / fmaxf(d, 1e-9f);
    float4 ba = reinterpret_cast<const float4*>(b1)[c4 * 2];
    float4 bb = reinterpret_cast<const float4*>(b1)[c4 * 2 + 1];
    float v0 = acc0 * inv + ba.x, v1 = acc1 * inv + ba.y;
    float v2 = acc2 * inv + ba.z, v3 = acc3 * inv + ba.w;
    float v4 = acc4 * inv + bb.x, v5 = acc5 * inv + bb.y;
    float v6 = acc6 * inv + bb.z, v7 = acc7 * inv + bb.w;
    v0 = v0 > 0.f ? v0 : __expf(v0) - 1.f;
    v1 = v1 > 0.f ? v1 : __expf(v1) - 1.f;
    v2 = v2 > 0.f ? v2 : __expf(v2) - 1.f;
    v3 = v3 > 0.f ? v3 : __expf(v3) - 1.f;
    v4 = v4 > 0.f ? v4 : __expf(v4) - 1.f;
    v5 = v5 > 0.f ? v5 : __expf(v5) - 1.f;
    v6 = v6 > 0.f ? v6 : __expf(v6) - 1.f;
    v7 = v7 > 0.f ? v7 : __expf(v7) - 1.f;
    const float* Wp = W2 + c4 * 8 * 3;
    float q0 = v0 * Wp[0] + v1 * Wp[3] + v2 * Wp[6] + v3 * Wp[9] +
               v4 * Wp[12] + v5 * Wp[15] + v6 * Wp[18] + v7 * Wp[21];
    float q1 = v0 * Wp[1] + v1 * Wp[4] + v2 * Wp[7] + v3 * Wp[10] +
               v4 * Wp[13] + v5 * Wp[16] + v6 * Wp[19] + v7 * Wp[22];
    float q2 = v0 * Wp[2] + v1 * Wp[5] + v2 * Wp[8] + v3 * Wp[11] +
               v4 * Wp[14] + v5 * Wp[17] + v6 * Wp[20] + v7 * Wp[23];
#pragma unroll
    for (int msk = 8; msk >= 1; msk >>= 1) {
      q0 += __shfl_xor(q0, msk);
      q1 += __shfl_xor(q1, msk);
      q2 += __shfl_xor(q2, msk);
    }
    if (c4 == 0) {
      z2el[n] = make_float4(q0, q1, q2, q0 * al2[0] + q1 * al2[1] + q2 * al2[2]);
      er2[n] = q0 * ar2[0] + q1 * ar2[1] + q2 * ar2[2];
    }
  }
}

// ---------------- layer-2: wave-per-node no-max softmax, 2-way unrolled (r20) ----------------
__global__ __launch_bounds__(256) void gat2_agg_kernel(const float4* __restrict__ z2el,
                                                       const float* __restrict__ er2,
                                                       const int* __restrict__ src,
                                                       const int* __restrict__ off,
                                                       const float* __restrict__ b2,
                                                       float* __restrict__ out) {
  int wid = threadIdx.x >> 6, lane = threadIdx.x & 63;
  int n = blockIdx.x * 4 + wid;
  if (n >= NNODES) return;
  int start = off[n], end = off[n + 1];
  float ern = er2[n];
  float dA = 0.f, x0 = 0.f, x1 = 0.f, x2 = 0.f;
  float dB = 0.f, y0 = 0.f, y1 = 0.f, y2 = 0.f;
  int base = start + lane;
  for (; base + 64 < end; base += 128) {
    float4 za = z2el[src[base]];
    float4 zb = z2el[src[base + 64]];
    float pa = __expf(lrelu(za.w + ern));
    float pb = __expf(lrelu(zb.w + ern));
    dA += pa; dB += pb;
    x0 = fmaf(pa, za.x, x0); x1 = fmaf(pa, za.y, x1); x2 = fmaf(pa, za.z, x2);
    y0 = fmaf(pb, zb.x, y0); y1 = fmaf(pb, zb.y, y1); y2 = fmaf(pb, zb.z, y2);
  }
  if (base < end) {
    float4 za = z2el[src[base]];
    float pa = __expf(lrelu(za.w + ern));
    dA += pa;
    x0 = fmaf(pa, za.x, x0); x1 = fmaf(pa, za.y, x1); x2 = fmaf(pa, za.z, x2);
  }
  float d = dA + dB, a0 = x0 + y0, a1 = x1 + y1, a2 = x2 + y2;
#pragma unroll
  for (int msk = 32; msk >= 1; msk >>= 1) {
    a0 += __shfl_xor(a0, msk);
    a1 += __shfl_xor(a1, msk);
    a2 += __shfl_xor(a2, msk);
    d += __shfl_xor(d, msk);
  }
  if (lane == 0) {
    float inv = 1.f / fmaxf(d, 1e-9f);
    out[n * 3 + 0] = a0 * inv + b2[0];
    out[n * 3 + 1] = a1 * inv + b2[1];
    out[n * 3 + 2] = a2 * inv + b2[2];
  }
}

extern "C" void kernel_launch(void* const* d_in, const int* in_sizes, int n_in,
                              void* d_out, int out_size, void* d_ws, size_t ws_size,
                              hipStream_t stream) {
  const float* features = (const float*)d_in[0];
  const int* src = (const int*)d_in[1];
  const int* dst = (const int*)d_in[2];
  const float* W1 = (const float*)d_in[3];
  const float* al1 = (const float*)d_in[4];
  const float* ar1 = (const float*)d_in[5];
  const float* b1 = (const float*)d_in[6];
  const float* W2 = (const float*)d_in[7];
  const float* al2 = (const float*)d_in[8];
  const float* ar2 = (const float*)d_in[9];
  const float* b2 = (const float*)d_in[10];
  float* out = (float*)d_out;
  int E = in_sizes[1];

  char* ws = (char*)d_ws;
  size_t o = 0;
  __half* z1h = (__half*)(ws + o);  o += (size_t)NNODES * HID * 2;
  float* el1 = (float*)(ws + o);    o += (size_t)NNODES * NH * 4;
  float* er1 = (float*)(ws + o);    o += (size_t)NNODES * NH * 4;
  float4* z2el = (float4*)(ws + o); o += (size_t)NNODES * 16;
  float* er2 = (float*)(ws + o);    o += (size_t)NNODES * 4;
  _Float16* BT_sw = (_Float16*)(ws + o); o += (size_t)HID * KP * 2;
  int* off = (int*)(ws + o);        o += (size_t)(NNODES + 1) * 4;

  prep_kernel<<<256 + (NNODES + 1 + 255) / 256, 256, 0, stream>>>(W1, BT_sw, dst, E, off);
  gemm1_mfma_kernel<<<(NNODES + BMG - 1) / BMG, 256, 0, stream>>>(features, BT_sw, al1, ar1,
                                                                  z1h, el1, er1);
  gat1_agg_kernel<<<(NNODES + 3) / 4, 256, 0, stream>>>(z1h, el1, er1, src, off, b1,
                                                        W2, al2, ar2, z2el, er2);
  gat2_agg_kernel<<<(NNODES + 3) / 4, 256, 0, stream>>>(z2el, er2, src, off, b2, out);
}

// Round 24
// 171.938 us; speedup vs baseline: 1.0463x; 1.0463x over previous
//
#include <hip/hip_runtime.h>
#include <hip/hip_fp16.h>
#include <math.h>

#define NNODES 100000
#define NEG_SLOPE 0.2f
#define FIN 500
#define KP 512     // padded K
#define HID 128    // heads*hidden
#define NH 4
#define BMG 128    // gemm rows per block (4 waves x 32 rows)

typedef __attribute__((ext_vector_type(8))) _Float16 half8v;
typedef __attribute__((ext_vector_type(4))) float f32x4;

__device__ __forceinline__ float lrelu(float x) { return x > 0.f ? x : NEG_SLOPE * x; }

__device__ __forceinline__ float sel4(float a0, float a1, float a2, float a3, int h) {
  float r = a0;
  r = (h == 1) ? a1 : r;
  r = (h == 2) ? a2 : r;
  r = (h == 3) ? a3 : r;
  return r;
}

// r8-proven conflict-free tile layout (measured SQ_LDS_BANK_CONFLICT = 0)
__device__ __forceinline__ int tile_off(int col, int slot) {
  return col * 32 + ((slot ^ ((col >> 1) & 3)) << 3);
}

// ---------------- prep: W1 -> pre-swizzled fp16 image  +  CSR offsets ----------------
__global__ __launch_bounds__(256) void prep_kernel(const float* __restrict__ W1,
                                                   _Float16* __restrict__ BT_sw,
                                                   const int* __restrict__ dst, int E,
                                                   int* __restrict__ off) {
  int b = blockIdx.x;
  if (b < 256) {
    int p = b * 256 + threadIdx.x;  // 65536
    int tile = p >> 12;
    int rem = p & 4095;
    int col = rem >> 5;
    int sw = (rem >> 3) & 3;
    int elem = rem & 7;
    int slot = sw ^ ((col >> 1) & 3);
    int k = tile * 32 + slot * 8 + elem;
    float v = (k < FIN) ? W1[k * HID + col] : 0.f;
    BT_sw[p] = (_Float16)v;
  } else {
    int n = (b - 256) * 256 + threadIdx.x;
    if (n > NNODES) return;
    int lo = 0, hi = E;
    while (lo < hi) {
      int mid = (lo + hi) >> 1;
      if (dst[mid] < n) lo = mid + 1; else hi = mid;
    }
    off[n] = lo;
  }
}

// ---------------- GEMM1: T4 counted-vmcnt + reg-staged fp16 A (48KB LDS) — frozen ----------------
__global__ __launch_bounds__(256, 3) void gemm1_mfma_kernel(const float* __restrict__ A,
                                                            const _Float16* __restrict__ BT_sw,
                                                            const float* __restrict__ al,
                                                            const float* __restrict__ ar,
                                                            __half* __restrict__ z1h,
                                                            float* __restrict__ el,
                                                            float* __restrict__ er) {
  __shared__ __align__(16) _Float16 Ash[3][4096];  // 3 x 8KB fp16 A tiles
  __shared__ __align__(16) _Float16 Bsh[3][4096];  // 3 x 8KB fp16 B tiles

  const int t = threadIdx.x;
  const int w = t >> 6, lane = t & 63;
  const int fr = lane & 15, ko = lane >> 4;
  const int bm = blockIdx.x * BMG;

  const int rowl = t >> 1, khalf = t & 1;
  const int arow = min(bm + rowl, NNODES - 1);
  const float* pArow = A + (size_t)arow * FIN;
  const int aoff0 = tile_off(rowl, khalf * 2);
  const int aoff1 = tile_off(rowl, khalf * 2 + 1);

#define LOAD_A(S, R0, R1, R2, R3)                                  \
  do {                                                             \
    const float* pa = pArow + (S) * 32 + khalf * 16;               \
    R0 = *(const f32x4*)(pa);                                      \
    R1 = *(const f32x4*)(pa + 4);                                  \
    R2 = *(const f32x4*)(pa + 8);                                  \
    R3 = *(const f32x4*)(pa + 12);                                 \
  } while (0)

#define LOAD_A_EDGE(R0, R1, R2, R3)                                  \
  do {                                                               \
    const float* pa = pArow + 480 + khalf * 16;                      \
    int _e1 = khalf ? 0 : 4, _e2 = khalf ? 0 : 8, _e3 = khalf ? 0 : 12; \
    R0 = *(const f32x4*)(pa);                                        \
    R1 = *(const f32x4*)(pa + _e1);                                  \
    R2 = *(const f32x4*)(pa + _e2);                                  \
    R3 = *(const f32x4*)(pa + _e3);                                  \
  } while (0)

#define CONV_WRITE(BUF, S, R0, R1, R2, R3)                         \
  do {                                                             \
    half8v h0, h1;                                                 \
    _Pragma("unroll")                                              \
    for (int i = 0; i < 4; i++) {                                  \
      h0[i] = (_Float16)R0[i];                                     \
      h0[i + 4] = (_Float16)R1[i];                                 \
      h1[i] = (_Float16)R2[i];                                     \
      h1[i + 4] = (_Float16)R3[i];                                 \
    }                                                              \
    if ((S) == 15 && khalf) {                                      \
      _Pragma("unroll")                                            \
      for (int i = 0; i < 4; i++) h0[i + 4] = (_Float16)0.f;       \
      _Pragma("unroll")                                            \
      for (int i = 0; i < 8; i++) h1[i] = (_Float16)0.f;           \
    }                                                              \
    *(half8v*)&Ash[BUF][aoff0] = h0;                               \
    *(half8v*)&Ash[BUF][aoff1] = h1;                               \
  } while (0)

#define STAGE_B(BUF, S)                                                                     \
  do {                                                                                      \
    _Pragma("unroll")                                                                       \
    for (int j = 0; j < 2; j++) {                                                           \
      int c = j * 256 + w * 64 + lane;                                                      \
      const _Float16* src = BT_sw + (size_t)(S) * 4096 + c * 8;                             \
      __builtin_amdgcn_global_load_lds(                                                     \
          (const __attribute__((address_space(1))) unsigned int*)src,                       \
          (__attribute__((address_space(3))) unsigned int*)&Bsh[BUF][c * 8], 16, 0, 0);     \
    }                                                                                       \
  } while (0)

  f32x4 acc[2][8];
#pragma unroll
  for (int i = 0; i < 2; i++)
#pragma unroll
    for (int j = 0; j < 8; j++) acc[i][j] = (f32x4){0.f, 0.f, 0.f, 0.f};

#define COMPUTE_STEP(BUF)                                                                   \
  do {                                                                                      \
    _Pragma("unroll")                                                                       \
    for (int mi = 0; mi < 2; mi++) {                                                        \
      half8v af = *(half8v*)&Ash[BUF][tile_off(w * 32 + mi * 16 + fr, ko)];                 \
      _Pragma("unroll")                                                                     \
      for (int ni = 0; ni < 8; ni++) {                                                      \
        half8v bf = *(half8v*)&Bsh[BUF][tile_off(ni * 16 + fr, ko)];                        \
        acc[mi][ni] = __builtin_amdgcn_mfma_f32_16x16x32_f16(af, bf, acc[mi][ni], 0, 0, 0); \
      }                                                                                     \
    }                                                                                       \
  } while (0)

  f32x4 e0, e1, e2, e3, o0, o1, o2, o3;

  LOAD_A(0, e0, e1, e2, e3);
  STAGE_B(0, 0);
  LOAD_A(1, o0, o1, o2, o3);
  STAGE_B(1, 1);

#pragma unroll
  for (int s = 0; s < 16; ++s) {
    const int cb = s % 3;
    if (s <= 14) {
      asm volatile("s_waitcnt vmcnt(6)" ::: "memory");
    } else {
      asm volatile("s_waitcnt vmcnt(0)" ::: "memory");
    }
    __builtin_amdgcn_sched_barrier(0);
    if ((s & 1) == 0) {
      CONV_WRITE(cb, s, e0, e1, e2, e3);
    } else {
      CONV_WRITE(cb, s, o0, o1, o2, o3);
    }
    asm volatile("s_waitcnt lgkmcnt(0)" ::: "memory");
    __builtin_amdgcn_sched_barrier(0);
    __builtin_amdgcn_s_barrier();
    __builtin_amdgcn_sched_barrier(0);
    if (s + 2 <= 14) {
      if ((s & 1) == 0) {
        LOAD_A(s + 2, e0, e1, e2, e3);
      } else {
        LOAD_A(s + 2, o0, o1, o2, o3);
      }
      STAGE_B((s + 2) % 3, s + 2);
    } else if (s + 2 == 15) {
      LOAD_A_EDGE(o0, o1, o2, o3);
      STAGE_B((s + 2) % 3, 15);
    }
    COMPUTE_STEP(cb);
  }

#undef LOAD_A
#undef LOAD_A_EDGE
#undef CONV_WRITE
#undef STAGE_B
#undef COMPUTE_STEP

  float alv[8], arv[8];
#pragma unroll
  for (int ni = 0; ni < 8; ni++) {
    alv[ni] = al[ni * 16 + fr];
    arv[ni] = ar[ni * 16 + fr];
  }
#pragma unroll
  for (int mi = 0; mi < 2; mi++) {
#pragma unroll
    for (int r = 0; r < 4; r++) {
      int grow = bm + w * 32 + mi * 16 + ko * 4 + r;
      bool ok = grow < NNODES;
      if (ok) {
#pragma unroll
        for (int ni = 0; ni < 8; ni++)
          z1h[(size_t)grow * HID + ni * 16 + fr] = __float2half(acc[mi][ni][r]);
      }
#pragma unroll
      for (int h = 0; h < 4; h++) {
        float cl = acc[mi][2 * h][r] * alv[2 * h] + acc[mi][2 * h + 1][r] * alv[2 * h + 1];
        float cr = acc[mi][2 * h][r] * arv[2 * h] + acc[mi][2 * h + 1][r] * arv[2 * h + 1];
#pragma unroll
        for (int m = 1; m <= 8; m <<= 1) {
          cl += __shfl_xor(cl, m);
          cr += __shfl_xor(cr, m);
        }
        if (fr == 0 && ok) {
          el[grow * NH + h] = cl;
          er[grow * NH + h] = cr;
        }
      }
    }
  }
}

// ---------------- layer-1 + proj2 FUSED, no-max softmax, 8-edges-in-flight agg (r22 best) ----------------
__global__ __launch_bounds__(256) void gat1_agg_kernel(const __half* __restrict__ z1h,
                                                       const float* __restrict__ el,
                                                       const float* __restrict__ er,
                                                       const int* __restrict__ src,
                                                       const int* __restrict__ off,
                                                       const float* __restrict__ b1,
                                                       const float* __restrict__ W2,
                                                       const float* __restrict__ al2,
                                                       const float* __restrict__ ar2,
                                                       float4* __restrict__ z2el,
                                                       float* __restrict__ er2) {
  int wid = threadIdx.x >> 6, lane = threadIdx.x & 63;
  int n = blockIdx.x * 4 + wid;
  if (n >= NNODES) return;
  __shared__ float p_sh[4][64 * 4];

  int start = off[n], end = off[n + 1];
  const float4* el4 = reinterpret_cast<const float4*>(el);
  float4 er4 = reinterpret_cast<const float4*>(er)[n];

  const int g = lane >> 4;
  const int c4 = lane & 15;
  const int headc = c4 >> 2;
  float aA0 = 0.f, aA1 = 0.f, aA2 = 0.f, aA3 = 0.f;
  float aA4 = 0.f, aA5 = 0.f, aA6 = 0.f, aA7 = 0.f;
  float aB0 = 0.f, aB1 = 0.f, aB2 = 0.f, aB3 = 0.f;
  float aB4 = 0.f, aB5 = 0.f, aB6 = 0.f, aB7 = 0.f;
  float d0 = 0.f, d1 = 0.f, d2 = 0.f, d3 = 0.f;

  for (int base = start; base < end; base += 64) {
    int cnt = min(64, end - base);
    int sr = 0;
    float p0 = 0.f, p1 = 0.f, p2 = 0.f, p3 = 0.f;
    if (lane < cnt) {
      sr = src[base + lane];
      float4 x = el4[sr];
      p0 = __expf(lrelu(x.x + er4.x));
      p1 = __expf(lrelu(x.y + er4.y));
      p2 = __expf(lrelu(x.z + er4.z));
      p3 = __expf(lrelu(x.w + er4.w));
      d0 += p0; d1 += p1; d2 += p2; d3 += p3;
    }
    *(float4*)&p_sh[wid][lane * 4] = make_float4(p0, p1, p2, p3);
    __builtin_amdgcn_wave_barrier();
    for (int i = 0; i < cnt; i += 8) {
      int ea = i + g, eb = i + 4 + g;
      bool va_ = ea < cnt, vb_ = eb < cnt;
      int sa = __shfl(sr, va_ ? ea : 0);
      int sb = __shfl(sr, vb_ ? eb : 0);
      float pa = va_ ? p_sh[wid][ea * 4 + headc] : 0.f;
      float pb = vb_ ? p_sh[wid][eb * 4 + headc] : 0.f;
      uint4 ra = reinterpret_cast<const uint4*>(z1h + (size_t)sa * HID)[c4];
      uint4 rb = reinterpret_cast<const uint4*>(z1h + (size_t)sb * HID)[c4];
      float2 va0 = __half22float2(*(__half2*)&ra.x);
      float2 va1 = __half22float2(*(__half2*)&ra.y);
      float2 va2 = __half22float2(*(__half2*)&ra.z);
      float2 va3 = __half22float2(*(__half2*)&ra.w);
      aA0 = fmaf(pa, va0.x, aA0); aA1 = fmaf(pa, va0.y, aA1);
      aA2 = fmaf(pa, va1.x, aA2); aA3 = fmaf(pa, va1.y, aA3);
      aA4 = fmaf(pa, va2.x, aA4); aA5 = fmaf(pa, va2.y, aA5);
      aA6 = fmaf(pa, va3.x, aA6); aA7 = fmaf(pa, va3.y, aA7);
      float2 vb0 = __half22float2(*(__half2*)&rb.x);
      float2 vb1 = __half22float2(*(__half2*)&rb.y);
      float2 vb2 = __half22float2(*(__half2*)&rb.z);
      float2 vb3 = __half22float2(*(__half2*)&rb.w);
      aB0 = fmaf(pb, vb0.x, aB0); aB1 = fmaf(pb, vb0.y, aB1);
      aB2 = fmaf(pb, vb1.x, aB2); aB3 = fmaf(pb, vb1.y, aB3);
      aB4 = fmaf(pb, vb2.x, aB4); aB5 = fmaf(pb, vb2.y, aB5);
      aB6 = fmaf(pb, vb3.x, aB6); aB7 = fmaf(pb, vb3.y, aB7);
    }
    __builtin_amdgcn_wave_barrier();
  }

  float acc0 = aA0 + aB0, acc1 = aA1 + aB1, acc2 = aA2 + aB2, acc3 = aA3 + aB3;
  float acc4 = aA4 + aB4, acc5 = aA5 + aB5, acc6 = aA6 + aB6, acc7 = aA7 + aB7;

#pragma unroll
  for (int msk = 32; msk >= 1; msk >>= 1) {
    d0 += __shfl_xor(d0, msk);
    d1 += __shfl_xor(d1, msk);
    d2 += __shfl_xor(d2, msk);
    d3 += __shfl_xor(d3, msk);
  }
#pragma unroll
  for (int msk = 16; msk <= 32; msk <<= 1) {
    acc0 += __shfl_xor(acc0, msk); acc1 += __shfl_xor(acc1, msk);
    acc2 += __shfl_xor(acc2, msk); acc3 += __shfl_xor(acc3, msk);
    acc4 += __shfl_xor(acc4, msk); acc5 += __shfl_xor(acc5, msk);
    acc6 += __shfl_xor(acc6, msk); acc7 += __shfl_xor(acc7, msk);
  }

  if (g == 0) {
    float dh = sel4(d0, d1, d2, d3, headc);
    float inv = 1.f / fmaxf(dh, 1e-9f);
    float4 ba = reinterpret_cast<const float4*>(b1)[c4 * 2];
    float4 bb = reinterpret_cast<const float4*>(b1)[c4 * 2 + 1];
    float v0 = acc0 * inv + ba.x, v1 = acc1 * inv + ba.y;
    float v2 = acc2 * inv + ba.z, v3 = acc3 * inv + ba.w;
    float v4 = acc4 * inv + bb.x, v5 = acc5 * inv + bb.y;
    float v6 = acc6 * inv + bb.z, v7 = acc7 * inv + bb.w;
    v0 = v0 > 0.f ? v0 : __expf(v0) - 1.f;
    v1 = v1 > 0.f ? v1 : __expf(v1) - 1.f;
    v2 = v2 > 0.f ? v2 : __expf(v2) - 1.f;
    v3 = v3 > 0.f ? v3 : __expf(v3) - 1.f;
    v4 = v4 > 0.f ? v4 : __expf(v4) - 1.f;
    v5 = v5 > 0.f ? v5 : __expf(v5) - 1.f;
    v6 = v6 > 0.f ? v6 : __expf(v6) - 1.f;
    v7 = v7 > 0.f ? v7 : __expf(v7) - 1.f;
    const float* Wp = W2 + c4 * 8 * 3;
    float q0 = v0 * Wp[0] + v1 * Wp[3] + v2 * Wp[6] + v3 * Wp[9] +
               v4 * Wp[12] + v5 * Wp[15] + v6 * Wp[18] + v7 * Wp[21];
    float q1 = v0 * Wp[1] + v1 * Wp[4] + v2 * Wp[7] + v3 * Wp[10] +
               v4 * Wp[13] + v5 * Wp[16] + v6 * Wp[19] + v7 * Wp[22];
    float q2 = v0 * Wp[2] + v1 * Wp[5] + v2 * Wp[8] + v3 * Wp[11] +
               v4 * Wp[14] + v5 * Wp[17] + v6 * Wp[20] + v7 * Wp[23];
#pragma unroll
    for (int msk = 8; msk >= 1; msk >>= 1) {
      q0 += __shfl_xor(q0, msk);
      q1 += __shfl_xor(q1, msk);
      q2 += __shfl_xor(q2, msk);
    }
    if (c4 == 0) {
      z2el[n] = make_float4(q0, q1, q2, q0 * al2[0] + q1 * al2[1] + q2 * al2[2]);
      er2[n] = q0 * ar2[0] + q1 * ar2[1] + q2 * ar2[2];
    }
  }
}

// ---------------- layer-2: wave-per-node no-max softmax, 2-way unrolled ----------------
__global__ __launch_bounds__(256) void gat2_agg_kernel(const float4* __restrict__ z2el,
                                                       const float* __restrict__ er2,
                                                       const int* __restrict__ src,
                                                       const int* __restrict__ off,
                                                       const float* __restrict__ b2,
                                                       float* __restrict__ out) {
  int wid = threadIdx.x >> 6, lane = threadIdx.x & 63;
  int n = blockIdx.x * 4 + wid;
  if (n >= NNODES) return;
  int start = off[n], end = off[n + 1];
  float ern = er2[n];
  float dA = 0.f, x0 = 0.f, x1 = 0.f, x2 = 0.f;
  float dB = 0.f, y0 = 0.f, y1 = 0.f, y2 = 0.f;
  int base = start + lane;
  for (; base + 64 < end; base += 128) {
    float4 za = z2el[src[base]];
    float4 zb = z2el[src[base + 64]];
    float pa = __expf(lrelu(za.w + ern));
    float pb = __expf(lrelu(zb.w + ern));
    dA += pa; dB += pb;
    x0 = fmaf(pa, za.x, x0); x1 = fmaf(pa, za.y, x1); x2 = fmaf(pa, za.z, x2);
    y0 = fmaf(pb, zb.x, y0); y1 = fmaf(pb, zb.y, y1); y2 = fmaf(pb, zb.z, y2);
  }
  if (base < end) {
    float4 za = z2el[src[base]];
    float pa = __expf(lrelu(za.w + ern));
    dA += pa;
    x0 = fmaf(pa, za.x, x0); x1 = fmaf(pa, za.y, x1); x2 = fmaf(pa, za.z, x2);
  }
  float d = dA + dB, a0 = x0 + y0, a1 = x1 + y1, a2 = x2 + y2;
#pragma unroll
  for (int msk = 32; msk >= 1; msk >>= 1) {
    a0 += __shfl_xor(a0, msk);
    a1 += __shfl_xor(a1, msk);
    a2 += __shfl_xor(a2, msk);
    d += __shfl_xor(d, msk);
  }
  if (lane == 0) {
    float inv = 1.f / fmaxf(d, 1e-9f);
    out[n * 3 + 0] = a0 * inv + b2[0];
    out[n * 3 + 1] = a1 * inv + b2[1];
    out[n * 3 + 2] = a2 * inv + b2[2];
  }
}

extern "C" void kernel_launch(void* const* d_in, const int* in_sizes, int n_in,
                              void* d_out, int out_size, void* d_ws, size_t ws_size,
                              hipStream_t stream) {
  const float* features = (const float*)d_in[0];
  const int* src = (const int*)d_in[1];
  const int* dst = (const int*)d_in[2];
  const float* W1 = (const float*)d_in[3];
  const float* al1 = (const float*)d_in[4];
  const float* ar1 = (const float*)d_in[5];
  const float* b1 = (const float*)d_in[6];
  const float* W2 = (const float*)d_in[7];
  const float* al2 = (const float*)d_in[8];
  const float* ar2 = (const float*)d_in[9];
  const float* b2 = (const float*)d_in[10];
  float* out = (float*)d_out;
  int E = in_sizes[1];

  char* ws = (char*)d_ws;
  size_t o = 0;
  __half* z1h = (__half*)(ws + o);  o += (size_t)NNODES * HID * 2;
  float* el1 = (float*)(ws + o);    o += (size_t)NNODES * NH * 4;
  float* er1 = (float*)(ws + o);    o += (size_t)NNODES * NH * 4;
  float4* z2el = (float4*)(ws + o); o += (size_t)NNODES * 16;
  float* er2 = (float*)(ws + o);    o += (size_t)NNODES * 4;
  _Float16* BT_sw = (_Float16*)(ws + o); o += (size_t)HID * KP * 2;
  int* off = (int*)(ws + o);        o += (size_t)(NNODES + 1) * 4;

  prep_kernel<<<256 + (NNODES + 1 + 255) / 256, 256, 0, stream>>>(W1, BT_sw, dst, E, off);
  gemm1_mfma_kernel<<<(NNODES + BMG - 1) / BMG, 256, 0, stream>>>(features, BT_sw, al1, ar1,
                                                                  z1h, el1, er1);
  gat1_agg_kernel<<<(NNODES + 3) / 4, 256, 0, stream>>>(z1h, el1, er1, src, off, b1,
                                                        W2, al2, ar2, z2el, er2);
  gat2_agg_kernel<<<(NNODES + 3) / 4, 256, 0, stream>>>(z2el, er2, src, off, b2, out);
}